// Round 10
// baseline (122.655 us; speedup 1.0000x reference)
//
#include <hip/hip_runtime.h>

// VQ-VAE VectorQuantizer forward, MI355X (gfx950)
// Round 10: fused scan with 2-tile waves (B-frags shared by 2 row-tiles) +
// code-split x2 (8 waves/block, 512 codes/wave), single 128KB LDS code buffer
// (ONE restage convoy), in-block cross-cg merge + loss + gather.
// out (f32 flat): [0..4194304) quantized, [4194304] loss,
//                 [4194305..+65536) indices (as float), [4259841..+65536) w.T

#define N_VEC 65536
#define D 64
#define K 1024
#define BETA 0.25f

#define OFF_Q    0
#define OFF_LOSS 4194304
#define OFF_IDX  4194305
#define OFF_WT   4259841

#define WS_WHI  0         // 128 KB frag-ordered fp16 hi plane
#define WS_WLO  131072    // 128 KB lo plane
#define WS_HNEG 262144    // 4 KB  -0.5*||w||^2 (f32)

// LDS layout (bytes)
#define LDS_W     0        // 2 cg x (32K hi + 32K lo) = 131072
#define LDS_HN    131072   // 4096   (all 1024 hneg)
#define LDS_MERGE 135168   // 4096   float2[256][2]
#define LDS_XN    139264   // 1024   float[256]
#define LDS_BI    140288   // 1024   int[256]
#define LDS_SZ    141312   // 138 KB -> 1 block/CU

typedef _Float16 v8h __attribute__((ext_vector_type(8)));
typedef float v16f __attribute__((ext_vector_type(16)));
typedef __attribute__((address_space(3))) void lds_void_t;
typedef __attribute__((address_space(1))) const void gbl_void_t;

// ---------------- prep (proven): w^T, frag fp16 hi/lo, hneg, loss=0
__global__ __launch_bounds__(256) void vq_prep(const float* __restrict__ w,
                                               char* __restrict__ ws,
                                               float* __restrict__ out) {
  __shared__ float s[2048];
  const int t = blockIdx.x, tid = threadIdx.x;

  const float4* src = (const float4*)(w + (size_t)t * 2048);
  float4 a = src[tid];
  float4 b = src[tid + 256];
  ((float4*)s)[tid] = a;
  ((float4*)s)[tid + 256] = b;

  float p0 = a.x * a.x + a.y * a.y + a.z * a.z + a.w * a.w;
  float p1 = b.x * b.x + b.y * b.y + b.z * b.z + b.w * b.w;
#pragma unroll
  for (int m = 1; m <= 8; m <<= 1) {
    p0 += __shfl_xor(p0, m, 64);
    p1 += __shfl_xor(p1, m, 64);
  }
  float* hn = (float*)(ws + WS_HNEG);
  if ((tid & 15) == 0) {
    hn[t * 32 + (tid >> 4)] = -0.5f * p0;
    hn[t * 32 + 16 + (tid >> 4)] = -0.5f * p1;
  }
  if (t == 0 && tid == 0) out[OFF_LOSS] = 0.f;
  __syncthreads();

  { // frag order: ((t*4+ks)*64 + l)*16B <-> w[t*32+(l&31)][ks*16+(l>>5)*8+j]
    const int ks = tid >> 6, l = tid & 63;
    const float* r0 = s + (l & 31) * 64 + ks * 16 + ((l >> 5) << 3);
    v8h hv, lv;
#pragma unroll
    for (int j = 0; j < 8; ++j) {
      float v = r0[j];
      _Float16 h = (_Float16)v;
      hv[j] = h;
      lv[j] = (_Float16)(v - (float)h);
    }
    const size_t eoff = ((size_t)(t * 4 + ks) * 64 + l) * 16;
    *(v8h*)(ws + WS_WHI + eoff) = hv;
    *(v8h*)(ws + WS_WLO + eoff) = lv;
  }

  { // w^T
    const int d = tid >> 2, k0 = (tid & 3) * 8;
#pragma unroll
    for (int j = 0; j < 8; ++j)
      out[OFF_WT + d * 1024 + t * 32 + k0 + j] = s[(k0 + j) * 64 + d];
  }
}

// ---------------- fused scan: 256 blocks x 512 thr. Block = 256 rows.
// wave wv: rg = wv>>1 (row-group, 64 rows = 2 tiles), cg = wv&1 (codes cg*512..+512)
__global__ __launch_bounds__(512, 2) void vq_scan(const float* __restrict__ x,
                                                  const float* __restrict__ w,
                                                  const char* __restrict__ ws,
                                                  float* __restrict__ out) {
  __shared__ __align__(16) char lds[LDS_SZ];
  const int tid = threadIdx.x;
  const int wv = tid >> 6, ln = tid & 63;
  const int rg = wv >> 1, cg = wv & 1;
  const int col = ln & 31, hi = ln >> 5;
  const int rowBlk = blockIdx.x * 256;
  const int rows0 = rowBlk + rg * 64;        // tile0: rows0, tile1: rows0+32

  // ---- stage fill f: for each cg region, slice (cg*2+f) hi+lo (128 KB total)
  auto stage = [&](int f) {
#pragma unroll
    for (int c = 0; c < 2; ++c) {
#pragma unroll
      for (int it = 0; it < 4; ++it) {
        const unsigned o = (unsigned)(it * 8192) + (unsigned)tid * 16;
        const unsigned so = (unsigned)((c * 2 + f) * 32768) + o;
        __builtin_amdgcn_global_load_lds((gbl_void_t*)(ws + WS_WHI + so),
                                         (lds_void_t*)(lds + c * 65536 + o), 16, 0, 0);
        __builtin_amdgcn_global_load_lds((gbl_void_t*)(ws + WS_WLO + so),
                                         (lds_void_t*)(lds + c * 65536 + 32768 + o), 16, 0, 0);
      }
    }
  };

  stage(0);
  if (tid < 256)
    __builtin_amdgcn_global_load_lds((gbl_void_t*)(ws + WS_HNEG + tid * 16),
                                     (lds_void_t*)(lds + LDS_HN + tid * 16), 16, 0, 0);

  // ---- x B-frags for BOTH tiles (fp16 hi/lo) + ||x||^2 — overlaps staging DMA
  v8h xh0[4], xl0[4], xh1[4], xl1[4];
  float xn0 = 0.f, xn1 = 0.f;
  {
    const float* xr0 = x + (size_t)(rows0 + col) * D + hi * 8;
    const float* xr1 = x + (size_t)(rows0 + 32 + col) * D + hi * 8;
#pragma unroll
    for (int ks = 0; ks < 4; ++ks) {
      float4 u0 = *(const float4*)(xr0 + ks * 16);
      float4 u1 = *(const float4*)(xr0 + ks * 16 + 4);
      float4 v0 = *(const float4*)(xr1 + ks * 16);
      float4 v1 = *(const float4*)(xr1 + ks * 16 + 4);
      float e0[8] = {u0.x, u0.y, u0.z, u0.w, u1.x, u1.y, u1.z, u1.w};
      float e1[8] = {v0.x, v0.y, v0.z, v0.w, v1.x, v1.y, v1.z, v1.w};
#pragma unroll
      for (int j = 0; j < 8; ++j) {
        _Float16 h0 = (_Float16)e0[j];
        xh0[ks][j] = h0;
        xl0[ks][j] = (_Float16)(e0[j] - (float)h0);
        xn0 = fmaf(e0[j], e0[j], xn0);
        _Float16 h1 = (_Float16)e1[j];
        xh1[ks][j] = h1;
        xl1[ks][j] = (_Float16)(e1[j] - (float)h1);
        xn1 = fmaf(e1[j], e1[j], xn1);
      }
    }
  }

  asm volatile("s_waitcnt vmcnt(0)" ::: "memory");
  __syncthreads();

  const float* hn = (const float*)(lds + LDS_HN);
  const char* wb = lds + cg * 65536;

  v8h ones = {};
  ones[0] = hi ? (_Float16)0.f : (_Float16)1.f;
  ones[1] = hi ? (_Float16)0.f : (_Float16)1.f;

  float best0 = -3.0e38f, best1 = -3.0e38f;
  int bi0 = 0, bi1 = 0;

#pragma unroll 1
  for (int f = 0; f < 2; ++f) {
#pragma unroll 2
    for (int ct = 0; ct < 8; ++ct) {
      v8h wh[4], wl[4];
#pragma unroll
      for (int ks = 0; ks < 4; ++ks) {
        wh[ks] = *(const v8h*)(wb + ct * 4096 + ks * 1024 + ln * 16);
        wl[ks] = *(const v8h*)(wb + 32768 + ct * 4096 + ks * 1024 + ln * 16);
      }
      const float hv = hn[cg * 512 + f * 256 + ct * 32 + col];
      const _Float16 bh = (_Float16)hv;
      const _Float16 bl = (_Float16)(hv - (float)bh);
      v8h bias = {};
      bias[0] = hi ? (_Float16)0.f : bh;
      bias[1] = hi ? (_Float16)0.f : bl;

      // two independent chains (one per row-tile), B-frags shared
      v16f a0 = {}, a1 = {};
      a0 = __builtin_amdgcn_mfma_f32_32x32x16_f16(bias, ones, a0, 0, 0, 0);
      a1 = __builtin_amdgcn_mfma_f32_32x32x16_f16(bias, ones, a1, 0, 0, 0);
#pragma unroll
      for (int ks = 0; ks < 4; ++ks) {
        a0 = __builtin_amdgcn_mfma_f32_32x32x16_f16(wh[ks], xh0[ks], a0, 0, 0, 0);
        a1 = __builtin_amdgcn_mfma_f32_32x32x16_f16(wh[ks], xh1[ks], a1, 0, 0, 0);
        a0 = __builtin_amdgcn_mfma_f32_32x32x16_f16(wl[ks], xh0[ks], a0, 0, 0, 0);
        a1 = __builtin_amdgcn_mfma_f32_32x32x16_f16(wl[ks], xh1[ks], a1, 0, 0, 0);
        a0 = __builtin_amdgcn_mfma_f32_32x32x16_f16(wh[ks], xl0[ks], a0, 0, 0, 0);
        a1 = __builtin_amdgcn_mfma_f32_32x32x16_f16(wh[ks], xl1[ks], a1, 0, 0, 0);
      }

      // branch-free argmax per tile (first-max == min code among maxima)
      const int cbase = cg * 512 + f * 256 + ct * 32 + 4 * hi;
      {
        float m0 = fmaxf(fmaxf(fmaxf(a0[0], a0[1]), fmaxf(a0[2], a0[3])),
                         fmaxf(fmaxf(a0[4], a0[5]), fmaxf(a0[6], a0[7])));
        m0 = fmaxf(m0, fmaxf(fmaxf(fmaxf(a0[8], a0[9]), fmaxf(a0[10], a0[11])),
                             fmaxf(fmaxf(a0[12], a0[13]), fmaxf(a0[14], a0[15]))));
        int tm[8];
#pragma unroll
        for (int r = 0; r < 8; ++r) {
          const int ca = cbase + (r & 3) + 8 * (r >> 2);
          const int cb = cbase + ((r + 8) & 3) + 8 * ((r + 8) >> 2);
          tm[r] = min((a0[r] == m0) ? ca : 0x7FFFFFFF,
                      (a0[r + 8] == m0) ? cb : 0x7FFFFFFF);
        }
        const int cmin = min(min(min(tm[0], tm[1]), min(tm[2], tm[3])),
                             min(min(tm[4], tm[5]), min(tm[6], tm[7])));
        const bool up = m0 > best0;
        bi0 = up ? cmin : bi0;
        best0 = up ? m0 : best0;
      }
      {
        float m1 = fmaxf(fmaxf(fmaxf(a1[0], a1[1]), fmaxf(a1[2], a1[3])),
                         fmaxf(fmaxf(a1[4], a1[5]), fmaxf(a1[6], a1[7])));
        m1 = fmaxf(m1, fmaxf(fmaxf(fmaxf(a1[8], a1[9]), fmaxf(a1[10], a1[11])),
                             fmaxf(fmaxf(a1[12], a1[13]), fmaxf(a1[14], a1[15]))));
        int tm[8];
#pragma unroll
        for (int r = 0; r < 8; ++r) {
          const int ca = cbase + (r & 3) + 8 * (r >> 2);
          const int cb = cbase + ((r + 8) & 3) + 8 * ((r + 8) >> 2);
          tm[r] = min((a1[r] == m1) ? ca : 0x7FFFFFFF,
                      (a1[r + 8] == m1) ? cb : 0x7FFFFFFF);
        }
        const int cmin = min(min(min(tm[0], tm[1]), min(tm[2], tm[3])),
                             min(min(tm[4], tm[5]), min(tm[6], tm[7])));
        const bool up = m1 > best1;
        bi1 = up ? cmin : bi1;
        best1 = up ? m1 : best1;
      }
    }

    if (f == 0) {   // the ONE restage convoy
      __syncthreads();
      stage(1);
      asm volatile("s_waitcnt vmcnt(0)" ::: "memory");
      __syncthreads();
    }
  }

  // ---- merge hi-halves (each covered half the codes per ct)
  {
    float ob = __shfl_xor(best0, 32, 64);
    int oi = __shfl_xor(bi0, 32, 64);
    if (ob > best0 || (ob == best0 && oi < bi0)) { best0 = ob; bi0 = oi; }
    ob = __shfl_xor(best1, 32, 64);
    oi = __shfl_xor(bi1, 32, 64);
    if (ob > best1 || (ob == best1 && oi < bi1)) { best1 = ob; bi1 = oi; }
    xn0 += __shfl_xor(xn0, 32, 64);
    xn1 += __shfl_xor(xn1, 32, 64);
  }

  // ---- publish per-row (score,idx) for this cg; xn once (cg0)
  {
    float2* mg = (float2*)(lds + LDS_MERGE);
    float* xna = (float*)(lds + LDS_XN);
    const int rl = rg * 64 + hi * 32 + col;     // all 64 lanes cover 64 rows
    mg[rl * 2 + cg] = make_float2(hi ? best1 : best0, (float)(hi ? bi1 : bi0));
    if (cg == 0) xna[rl] = hi ? xn1 : xn0;
  }
  __syncthreads();

  // ---- cross-cg merge, idx write, loss, then cooperative gather
  const float2* mg = (const float2*)(lds + LDS_MERGE);
  const float* xna = (const float*)(lds + LDS_XN);
  int* s_bi = (int*)(lds + LDS_BI);
  float lr = 0.f;
  if (tid < 256) {
    const float2 c0 = mg[tid * 2], c1 = mg[tid * 2 + 1];
    float sbest = c0.x, fi = c0.y;
    if (c1.x > sbest) { sbest = c1.x; fi = c1.y; }  // tie -> cg0 (smaller idx)
    out[OFF_IDX + rowBlk + tid] = fi;
    s_bi[tid] = (int)fi;
    lr = xna[tid] - 2.f * sbest;     // ||x-w||^2 = ||x||^2 - 2*score
  }
#pragma unroll
  for (int off = 32; off >= 1; off >>= 1) lr += __shfl_xor(lr, off, 64);
  if (ln == 0) atomicAdd(out + OFF_LOSS, lr * (BETA / (float)(N_VEC * D)));

  __syncthreads();
#pragma unroll 4
  for (int it = 0; it < 32; ++it) {    // 8 rows x 64 lanes = 2 KB per iter
    const int rl = it * 8 + wv;
    const float v = w[(size_t)s_bi[rl] * 64 + ln];
    out[OFF_Q + (size_t)(rowBlk + rl) * 64 + ln] = v;
  }
}

extern "C" void kernel_launch(void* const* d_in, const int* in_sizes, int n_in,
                              void* d_out, int out_size, void* d_ws, size_t ws_size,
                              hipStream_t stream) {
  const float* x = (const float*)d_in[0];
  const float* w = (const float*)d_in[1];
  float* out = (float*)d_out;
  char* ws = (char*)d_ws;

  vq_prep<<<32, 256, 0, stream>>>(w, ws, out);
  vq_scan<<<N_VEC / 256, 512, 0, stream>>>(x, w, ws, out);
}